// Round 2
// baseline (469.467 us; speedup 1.0000x reference)
//
#include <hip/hip_runtime.h>
#include <stdint.h>

// MultiHeadAttention_62766652064333: DM=512 H=8 B=8 SQ=SK=1024. f32 I/O, int32 mask.
// bf16 MFMA compute (f32 accumulate), m97-structure TN GEMM (128x128 tile, 256 thr,
// global_load_lds width=16, unpadded [128][32] LDS tiles, 2-barrier K-loop).
//
// Pipeline (v3 = v2 minus hipMemsetAsync; bvs computed in prep_w tail blocks):
//   prep_w:        Wq^T, Wk^T bf16; Wv plain bf16; Wsum^T bf16; bvs = bv@Wsum (2 tail blocks)
//   prep_qkv+Wct:  Q,K,V f32->bf16 (6144 blks) MERGED with Wc^T = (Wv@Wsum)^T GEMM (16 blks)
//   gemm_qkvv:     z=0..7  Qlb = Qb@Wqt^T + bq          (bf16, mode0)
//                  z=8..15 Klb = Kb@Wkt^T + bk          (bf16, mode0)
//                  z=16..23 Vwt = (Vb@Wct^T + bvs)^T    (bf16, mode1)  -- 768 blocks, 3/CU
//   gemm scores:   Sb = bf16(Qlb@Klb^T * 1/sqrt(512) + mask*(-1e9))    (mode0, bf16 out)
//   softmax:       Sb -> f32 att slots 0..7 (d_out) + bf16 attb (d_ws)
//   gemm Y:        Yout = attb@Vwt^T + bl (f32, mode2)
//
// Math: att rows sum to 1 so adding bvs[n]=(bv@Wsum)[n] to each Vw column yields exactly
// +bvs in Y. Wsum = sum_h Wl[h] since all 8 'heads' are identical (jnp.tile in ref).

typedef unsigned short u16;
typedef __attribute__((ext_vector_type(8))) short bf16x8;        // MFMA A/B frag
typedef __attribute__((ext_vector_type(8))) unsigned short u16x8;
typedef __attribute__((ext_vector_type(4))) unsigned short u16x4;
typedef __attribute__((ext_vector_type(4))) float f32x4;         // MFMA C/D frag

__device__ __forceinline__ u16 f2bf(float f) {
    union { float f; unsigned int u; } v; v.f = f;
    v.u += 0x7fffu + ((v.u >> 16) & 1u);   // round-to-nearest-even
    return (u16)(v.u >> 16);
}
__device__ __forceinline__ float bf2f(u16 u) {
    union { unsigned int u; float f; } v; v.u = (unsigned int)u << 16;
    return v.f;
}

__device__ __forceinline__ void gld16(const u16* g, u16* l) {
#if __has_builtin(__builtin_amdgcn_global_load_lds)
    __builtin_amdgcn_global_load_lds(
        (const __attribute__((address_space(1))) void*)g,
        (__attribute__((address_space(3))) void*)l, 16, 0, 0);
#else
    *(uint4*)l = *(const uint4*)g;
#endif
}

// ---- shared TN GEMM core: acc[4][4] (+=) A[m0..m0+128, :] @ B[n0..n0+128, :]^T ----
// A[M,K], B[N,K] row-major bf16; K%32==0; rows 16B-aligned.
__device__ __forceinline__ void gemm_core(
    const u16* __restrict__ Ab, const u16* __restrict__ Bb,
    int K, int lda, int ldb, int m0, int n0, int t,
    u16 (*As)[32], u16 (*Bs)[32], f32x4 acc[4][4])
{
    const int lane = t & 63;
    const int wm = ((t >> 6) & 1) * 64;
    const int wn = (t >> 7) * 64;
    const int sr = t >> 2, sc = (t & 3) * 8;      // staging: thread t -> 16B at flat t*16
    const int fr = lane & 15, fk = (lane >> 4) * 8;

    for (int k0 = 0; k0 < K; k0 += 32) {
        const u16* ap = Ab + (long)(m0 + sr) * lda + (k0 + sc);
        const u16* bp = Bb + (long)(n0 + sr) * ldb + (k0 + sc);
        gld16(ap,             &As[sr][sc]);
        gld16(ap + 64L * lda, &As[sr + 64][sc]);
        gld16(bp,             &Bs[sr][sc]);
        gld16(bp + 64L * ldb, &Bs[sr + 64][sc]);
        __syncthreads();

        bf16x8 af[4], bfv[4];
        #pragma unroll
        for (int i = 0; i < 4; i++) af[i]  = *(const bf16x8*)&As[wm + i*16 + fr][fk];
        #pragma unroll
        for (int j = 0; j < 4; j++) bfv[j] = *(const bf16x8*)&Bs[wn + j*16 + fr][fk];
        #pragma unroll
        for (int i = 0; i < 4; i++)
            #pragma unroll
            for (int j = 0; j < 4; j++)
                acc[i][j] = __builtin_amdgcn_mfma_f32_16x16x32_bf16(af[i], bfv[j], acc[i][j], 0, 0, 0);
        __syncthreads();
    }
}

// Epilogue. result = acc*scale + bias[col] + mask[col]*(-1e9)
// mode 0: bf16 C row-major.  mode 1: bf16 C^T (C[col*ldc+row]).  mode 2: f32 C row-major.
// C/D frag layout: col = lane&15, row = (lane>>4)*4 + r   [HW-verified m89/m91]
__device__ __forceinline__ void gemm_epilogue(
    int mode, void* Cv, const float* bias, const int* maskp,
    float scale, int ldc, int m0, int n0, int t, f32x4 acc[4][4])
{
    const int lane = t & 63;
    const int wm = ((t >> 6) & 1) * 64;
    const int wn = (t >> 7) * 64;
    const int cl = lane & 15, rl = (lane >> 4) * 4;

    float badd[4];
    #pragma unroll
    for (int j = 0; j < 4; j++) {
        int col = n0 + wn + j * 16 + cl;
        float v = bias ? bias[col] : 0.f;
        if (maskp) v += (float)maskp[col] * (-1e9f);
        badd[j] = v;
    }

    if (mode == 1) {
        u16* C = (u16*)Cv;
        #pragma unroll
        for (int i = 0; i < 4; i++)
            #pragma unroll
            for (int r = 0; r < 4; r++) {
                long row = m0 + wm + i * 16 + rl + r;
                #pragma unroll
                for (int j = 0; j < 4; j++)
                    C[(long)(n0 + wn + j * 16 + cl) * ldc + row] =
                        f2bf(acc[i][j][r] * scale + badd[j]);
            }
    } else if (mode == 2) {
        float* C = (float*)Cv;
        #pragma unroll
        for (int i = 0; i < 4; i++)
            #pragma unroll
            for (int r = 0; r < 4; r++) {
                float* crow = C + (long)(m0 + wm + i * 16 + rl + r) * ldc;
                #pragma unroll
                for (int j = 0; j < 4; j++)
                    crow[n0 + wn + j * 16 + cl] = acc[i][j][r] * scale + badd[j];
            }
    } else {
        u16* C = (u16*)Cv;
        #pragma unroll
        for (int i = 0; i < 4; i++)
            #pragma unroll
            for (int r = 0; r < 4; r++) {
                u16* crow = C + (long)(m0 + wm + i * 16 + rl + r) * ldc;
                #pragma unroll
                for (int j = 0; j < 4; j++)
                    crow[n0 + wn + j * 16 + cl] = f2bf(acc[i][j][r] * scale + badd[j]);
            }
    }
}

// Generic batched TN GEMM (runtime mode). sC in elements of the C type.
__global__ __launch_bounds__(256, 2)
void gemm_tn(const u16* __restrict__ A, const u16* __restrict__ B, void* __restrict__ Cv,
             const float* __restrict__ bias, const int* __restrict__ mask,
             int K, int lda, int ldb, int ldc,
             long sA, long sB, long sC, long sMask, float scale, int mode)
{
    __shared__ __align__(16) u16 As[128][32];
    __shared__ __align__(16) u16 Bs[128][32];
    const int bz = blockIdx.z;
    const int m0 = blockIdx.x * 128, n0 = blockIdx.y * 128;
    const int t = threadIdx.x;

    f32x4 acc[4][4];
    #pragma unroll
    for (int i = 0; i < 4; i++)
        #pragma unroll
        for (int j = 0; j < 4; j++) acc[i][j] = (f32x4){0.f, 0.f, 0.f, 0.f};

    gemm_core(A + (long)bz * sA, B + (long)bz * sB, K, lda, ldb, m0, n0, t, As, Bs, acc);

    void* Cb = (mode == 2) ? (void*)((float*)Cv + (long)bz * sC)
                           : (void*)((u16*)Cv + (long)bz * sC);
    const int* maskp = mask ? mask + (long)bz * sMask : nullptr;
    gemm_epilogue(mode, Cb, bias, maskp, scale, ldc, m0, n0, t, acc);
}

// Merged projections: grid (8,4,24). z/8: 0 -> Qlb, 1 -> Klb, 2 -> Vwt (transposed out).
__global__ __launch_bounds__(256, 2)
void gemm_qkvv(const u16* __restrict__ Qb, const u16* __restrict__ Kb,
               const u16* __restrict__ Vb, const u16* __restrict__ Wqt,
               const u16* __restrict__ Wkt, const u16* __restrict__ Wct,
               u16* __restrict__ Qlb, u16* __restrict__ Klb, u16* __restrict__ Vwt,
               const float* __restrict__ bq, const float* __restrict__ bk,
               const float* __restrict__ bvs)
{
    __shared__ __align__(16) u16 As[128][32];
    __shared__ __align__(16) u16 Bs[128][32];
    const int z = blockIdx.z, seg = z >> 3, b = z & 7;
    const int m0 = blockIdx.x * 128, n0 = blockIdx.y * 128;
    const int t = threadIdx.x;
    const long sQ = 524288L;

    const u16* A; const u16* B; u16* C; const float* bias; int ldc, mode;
    if (seg == 0)      { A = Qb + b * sQ; B = Wqt; C = Qlb + b * sQ; bias = bq;  ldc = 512;  mode = 0; }
    else if (seg == 1) { A = Kb + b * sQ; B = Wkt; C = Klb + b * sQ; bias = bk;  ldc = 512;  mode = 0; }
    else               { A = Vb + b * sQ; B = Wct; C = Vwt + b * sQ; bias = bvs; ldc = 1024; mode = 1; }

    f32x4 acc[4][4];
    #pragma unroll
    for (int i = 0; i < 4; i++)
        #pragma unroll
        for (int j = 0; j < 4; j++) acc[i][j] = (f32x4){0.f, 0.f, 0.f, 0.f};

    gemm_core(A, B, 512, 512, 512, m0, n0, t, As, Bs, acc);
    gemm_epilogue(mode, C, bias, nullptr, 1.f, ldc, m0, n0, t, acc);
}

// Prep weights: blocks 0..4095: Wq^T, Wk^T bf16; Wv plain bf16; Wsum^T bf16.
// Blocks 4096..4097: bvs[n] = sum_k bv[k]*Wsum[k][n] (exact; skips zero bv[k] --
// free for this problem's zero biases, no atomics, no memset needed).
__global__ __launch_bounds__(256)
void prep_w(const float* __restrict__ Wq, const float* __restrict__ Wk,
            const float* __restrict__ Wv, const float* __restrict__ Wl,
            const float* __restrict__ bv,
            u16* __restrict__ Wqt, u16* __restrict__ Wkt,
            u16* __restrict__ Wvb, u16* __restrict__ Wst, float* __restrict__ bvs)
{
    const int bx = blockIdx.x;
    if (bx >= 4096) {
        int n = (bx - 4096) * 256 + threadIdx.x;          // 0..511
        if (n < 512) {
            float acc = 0.f;
            for (int k = 0; k < 512; k++) {
                float bvk = bv[k];
                if (bvk != 0.f) {
                    float s = 0.f;
                    #pragma unroll
                    for (int h = 0; h < 8; h++) s += Wl[((long)h * 512 + k) * 512 + n];
                    acc += bvk * s;
                }
            }
            bvs[n] = acc;
        }
        return;
    }
    long id = (long)bx * 256 + threadIdx.x;               // < 1048576
    int seg = (int)(id >> 18);                            // /262144
    long j = id & 262143L;
    int n = (int)(j & 511), k = (int)(j >> 9);
    if (seg == 0) {
        Wqt[(long)n * 512 + k] = f2bf(Wq[(long)k * 512 + n]);
    } else if (seg == 1) {
        Wkt[(long)n * 512 + k] = f2bf(Wk[(long)k * 512 + n]);
    } else if (seg == 2) {
        Wvb[j] = f2bf(Wv[j]);                             // plain copy (A-operand of Wc GEMM)
    } else {
        float s = 0.f;
        #pragma unroll
        for (int h = 0; h < 8; h++) s += Wl[((long)h * 512 + k) * 512 + n];
        Wst[(long)n * 512 + k] = f2bf(s);
    }
}

// Q,K,V f32->bf16 (blocks 0..6143) merged with Wc^T GEMM (blocks 6144..6159):
// Wct[n][k] = (Wv@Wsum)[k][n], via TN core A=Wvb [512,512], B=Wst [512,512], mode1.
__global__ __launch_bounds__(256, 2)
void prep_qkv_wct(const float* __restrict__ Q, const float* __restrict__ K,
                  const float* __restrict__ V, u16* __restrict__ Qb,
                  u16* __restrict__ Kb, u16* __restrict__ Vb,
                  const u16* __restrict__ Wvb, const u16* __restrict__ Wst,
                  u16* __restrict__ Wct)
{
    __shared__ __align__(16) u16 As[128][32];
    __shared__ __align__(16) u16 Bs[128][32];
    const int bx = blockIdx.x;
    if (bx < 6144) {
        long id = (long)bx * 256 + threadIdx.x;           // < 1572864
        int seg = (int)(id >> 19);                         // /524288
        long e = (id & 524287L) * 8;
        const float* s = seg == 0 ? Q : (seg == 1 ? K : V);
        u16* d = seg == 0 ? Qb : (seg == 1 ? Kb : Vb);
        float4 lo = *(const float4*)(s + e);
        float4 hi = *(const float4*)(s + e + 4);
        u16x8 r;
        r[0]=f2bf(lo.x); r[1]=f2bf(lo.y); r[2]=f2bf(lo.z); r[3]=f2bf(lo.w);
        r[4]=f2bf(hi.x); r[5]=f2bf(hi.y); r[6]=f2bf(hi.z); r[7]=f2bf(hi.w);
        *(u16x8*)(d + e) = r;
        return;
    }
    const int bid = bx - 6144;                            // 0..15
    const int m0 = (bid & 3) * 128, n0 = (bid >> 2) * 128;
    const int t = threadIdx.x;
    f32x4 acc[4][4];
    #pragma unroll
    for (int i = 0; i < 4; i++)
        #pragma unroll
        for (int j = 0; j < 4; j++) acc[i][j] = (f32x4){0.f, 0.f, 0.f, 0.f};
    gemm_core(Wvb, Wst, 512, 512, 512, m0, n0, t, As, Bs, acc);
    gemm_epilogue(1, Wct, nullptr, nullptr, 1.f, 512, m0, n0, t, acc);
}

// One block per (q,b): softmax of bf16 scores row; writes f32 att rows to all 8 slots
// of d_out AND a bf16 copy to attb (d_ws) for the Y GEMM.
__global__ __launch_bounds__(256)
void softmax_rep(const u16* __restrict__ Sb, float* __restrict__ att,
                 u16* __restrict__ attb)
{
    const int q = blockIdx.x, b = blockIdx.y;
    const int t = threadIdx.x;
    const u16* row = Sb + ((long)b * 1024 + q) * 1024;

    u16x4 xv = *(const u16x4*)(row + t * 4);
    float x[4] = { bf2f(xv[0]), bf2f(xv[1]), bf2f(xv[2]), bf2f(xv[3]) };

    float m = fmaxf(fmaxf(x[0], x[1]), fmaxf(x[2], x[3]));
    #pragma unroll
    for (int o = 32; o > 0; o >>= 1) m = fmaxf(m, __shfl_xor(m, o));
    __shared__ float red[4];
    const int w = t >> 6;
    if ((t & 63) == 0) red[w] = m;
    __syncthreads();
    m = fmaxf(fmaxf(red[0], red[1]), fmaxf(red[2], red[3]));
    __syncthreads();

    float e[4], s = 0.f;
    #pragma unroll
    for (int i = 0; i < 4; i++) { e[i] = __expf(x[i] - m); s += e[i]; }
    #pragma unroll
    for (int o = 32; o > 0; o >>= 1) s += __shfl_xor(s, o);
    if ((t & 63) == 0) red[w] = s;
    __syncthreads();
    s = red[0] + red[1] + red[2] + red[3];
    float inv = 1.f / s;

    float a0 = e[0]*inv, a1 = e[1]*inv, a2 = e[2]*inv, a3 = e[3]*inv;
    float4 ov = make_float4(a0, a1, a2, a3);
    #pragma unroll
    for (int h = 0; h < 8; h++)
        *(float4*)(att + (((long)b * 8 + h) * 1024 + q) * 1024 + t * 4) = ov;
    u16x4 bo; bo[0]=f2bf(a0); bo[1]=f2bf(a1); bo[2]=f2bf(a2); bo[3]=f2bf(a3);
    *(u16x4*)(attb + ((long)b * 1024 + q) * 1024 + t * 4) = bo;
}

extern "C" void kernel_launch(void* const* d_in, const int* in_sizes, int n_in,
                              void* d_out, int out_size, void* d_ws, size_t ws_size,
                              hipStream_t stream)
{
    (void)in_sizes; (void)n_in; (void)out_size; (void)ws_size;

    const float* Q    = (const float*)d_in[0];
    const float* Kin  = (const float*)d_in[1];
    const float* V    = (const float*)d_in[2];
    const int*   mask = (const int*)d_in[3];
    const float* Wq   = (const float*)d_in[4];
    const float* bq   = (const float*)d_in[5];
    const float* Wk   = (const float*)d_in[6];
    const float* bk   = (const float*)d_in[7];
    const float* Wv   = (const float*)d_in[8];
    const float* bv   = (const float*)d_in[9];
    const float* Wl   = (const float*)d_in[10];
    const float* bl   = (const float*)d_in[11];

    float* out  = (float*)d_out;
    float* Yout = out;                            // [8,1024,512] f32
    float* att  = out + 4194304L;                 // [8,8,1024,1024] f32

    // bf16 scratch in d_ws (~86.5 MB)
    u16*   w    = (u16*)d_ws;
    float* bvs  = (float*)w;                      // 512 f32 (occupies 1024 u16)
    u16*   Qb   = w + 1024;                       // 4194304 each for Q/K/V
    u16*   Kb   = Qb + 4194304L;
    u16*   Vb   = Kb + 4194304L;
    u16*   Wqt  = Vb + 4194304L;                  // 262144 each
    u16*   Wkt  = Wqt + 262144L;
    u16*   Wvb  = Wkt + 262144L;
    u16*   Wst  = Wvb + 262144L;
    u16*   Wct  = Wst + 262144L;
    u16*   Qlb  = Wct + 262144L;                  // 4194304
    u16*   Klb  = Qlb + 4194304L;
    u16*   Vwt  = Klb + 4194304L;                 // [b][512][1024]
    u16*   Sb   = Vwt + 4194304L;                 // [b][1024][1024] bf16 scores
    u16*   attb = Sb + 8388608L;                  // [b][1024][1024] bf16 att

    const long sQ  = 524288L;                     // per-batch 1024x512 (elems)
    const long sAt = 1048576L;                    // per-batch 1024x1024 (elems)
    const float isc = 0.04419417382415922f;       // 1/sqrt(512)

    prep_w<<<dim3(4098), dim3(256), 0, stream>>>(Wq, Wk, Wv, Wl, bv,
                                                 Wqt, Wkt, Wvb, Wst, bvs);

    prep_qkv_wct<<<dim3(6160), dim3(256), 0, stream>>>(Q, Kin, V, Qb, Kb, Vb,
                                                       Wvb, Wst, Wct);

    // Qlb/Klb/Vwt in one launch: 768 blocks (~3 blocks/CU)
    gemm_qkvv<<<dim3(8, 4, 24), dim3(256), 0, stream>>>(
        Qb, Kb, Vb, Wqt, Wkt, Wct, Qlb, Klb, Vwt, bq, bk, bvs);

    // Sb = bf16(Qlb@Klb^T * isc + mask*(-1e9)): M=N=1024 K=512, 512 blocks
    gemm_tn<<<dim3(8, 8, 8), dim3(256), 0, stream>>>(
        Qlb, Klb, Sb, nullptr, mask, 512, 512, 512, 1024,
        sQ, sQ, sAt, 1024L, isc, 0);

    softmax_rep<<<dim3(1024, 8), dim3(256), 0, stream>>>(Sb, att, attb);

    // Y = attb@Vwt^T + bl (f32): M=1024 N=512 K=1024
    gemm_tn<<<dim3(8, 4, 8), dim3(256), 0, stream>>>(
        attb, Vwt, Yout, bl, nullptr, 1024, 1024, 1024, 512,
        sAt, sQ, sQ, 0L, 1.f, 2);
}